// Round 2
// baseline (1418.150 us; speedup 1.0000x reference)
//
#include <hip/hip_runtime.h>

typedef __bf16 bf16x8 __attribute__((ext_vector_type(8)));
typedef __bf16 bf16x4 __attribute__((ext_vector_type(4)));
typedef float  f32x4  __attribute__((ext_vector_type(4)));

#define HW   256
#define HW2  65536

// 4096 blocks: pair = blk>>2 (b*32+o), h-tile = (blk>>1)&1, w-half = blk&1.
// 512 threads = 8 waves; wave w owns h rows [h0+16w, h0+16w+16), w-cols [w0, w0+128).
// Fused flash-style per 64-col g-chunk: A->accc prefetch, stage K (full w) ->
// QK^T -> online softmax -> stage V^T (w-half, aliased with K) -> PV rescale.
// QK/softmax duplicated across the two w-half blocks (FLOP headroom is huge);
// oacc shrinks 16->8 tiles (32 AGPR) so everything fits 128 unified regs
// -> 2 blocks/CU without spills. LDS = 33.8K (K/V^T union) + 18.4K (P) + 1K.
__global__ __launch_bounds__(512, 4) void attn_kernel(
    const float* __restrict__ x1, const float* __restrict__ x2,
    const float* __restrict__ Wq, const float* __restrict__ bq,
    const float* __restrict__ Wk, const float* __restrict__ bk,
    const float* __restrict__ Wv, const float* __restrict__ bv,
    const float* __restrict__ Wa, const float* __restrict__ ba,
    float* __restrict__ out)
{
    // Union: K chunk (64 g-rows x 264 bf16, stride 528B) lives in QK phase;
    //        V^T chunk (128 w-rows x 72 bf16, stride 144B) lives in PV phase.
    __shared__ __align__(16) __bf16 sU[64 * 264];     // 33792 B
    __shared__ __align__(16) __bf16 sPc[128 * 72];    // 18432 B, P chunk (128h x 64g)
    __shared__ float sFac[128];                       // per-row rescale factor
    __shared__ float sRow[128];                       // final row sums

    const int tid  = threadIdx.x;
    const int wid  = tid >> 6;      // wave 0..7
    const int lane = tid & 63;
    const int quad = lane >> 4;     // 0..3
    const int c    = lane & 15;     // 0..15

    const int blk  = blockIdx.x;
    const int pair = blk >> 2;      // b*32 + o
    const int ht   = (blk >> 1) & 1;
    const int wh   = blk & 1;
    const int b    = pair >> 5;
    const int o    = pair & 31;
    const int h0   = ht * 128;
    const int w0   = wh * 128;

    const float wq0 = Wq[o*3+0], wq1 = Wq[o*3+1], wq2 = Wq[o*3+2], bqv = bq[o];
    const float wk0 = Wk[o*3+0], wk1 = Wk[o*3+1], wk2 = Wk[o*3+2], bkv = bk[o];
    const float wv0 = Wv[o*3+0], wv1 = Wv[o*3+1], wv2 = Wv[o*3+2], bvv = bv[o];
    const float wa0 = Wa[o*3+0], wa1 = Wa[o*3+1], wa2 = Wa[o*3+2], bav = ba[o];
    const float inv = 1.0f / 256.0f;

    const float* x1b = x1 + b * 3 * HW2;
    const float* x2b = x2 + b * 3 * HW2;

    // ---------- Q fragments (A-operand), pre-scaled by inv_scale ----------
    // A[m=lane&15][k=quad*8+j]; m -> h row, k -> w (full 256-w reduction)
    bf16x8 qf[8];
    {
        const int hq = h0 + 16*wid + c;
        const float* r0 = x1b + 0*HW2 + hq*HW;
        const float* r1 = x1b + 1*HW2 + hq*HW;
        const float* r2 = x1b + 2*HW2 + hq*HW;
#pragma unroll
        for (int kt = 0; kt < 8; ++kt) {
            const int wc = 32*kt + 8*quad;
            float4 a0 = *(const float4*)(r0 + wc), a1 = *(const float4*)(r0 + wc + 4);
            float4 b0 = *(const float4*)(r1 + wc), b1 = *(const float4*)(r1 + wc + 4);
            float4 c0 = *(const float4*)(r2 + wc), c1 = *(const float4*)(r2 + wc + 4);
            bf16x8 q;
            q[0] = (__bf16)((wq0*a0.x + wq1*b0.x + wq2*c0.x + bqv) * inv);
            q[1] = (__bf16)((wq0*a0.y + wq1*b0.y + wq2*c0.y + bqv) * inv);
            q[2] = (__bf16)((wq0*a0.z + wq1*b0.z + wq2*c0.z + bqv) * inv);
            q[3] = (__bf16)((wq0*a0.w + wq1*b0.w + wq2*c0.w + bqv) * inv);
            q[4] = (__bf16)((wq0*a1.x + wq1*b1.x + wq2*c1.x + bqv) * inv);
            q[5] = (__bf16)((wq0*a1.y + wq1*b1.y + wq2*c1.y + bqv) * inv);
            q[6] = (__bf16)((wq0*a1.z + wq1*b1.z + wq2*c1.z + bqv) * inv);
            q[7] = (__bf16)((wq0*a1.w + wq1*b1.w + wq2*c1.w + bqv) * inv);
            qf[kt] = q;
        }
    }

    // O^T accumulator (w-half): oacc[wt] elem r = O^T[w=w0+16wt+4quad+r][h=16wid+c]
    f32x4 oacc[8];
#pragma unroll
    for (int t = 0; t < 8; ++t) oacc[t] = (f32x4){0.f, 0.f, 0.f, 0.f};
    // online softmax state, row h = h0 + 16wid + 4quad + r
    float m_run[4] = {-1e30f, -1e30f, -1e30f, -1e30f};
    float l_run[4] = {0.f, 0.f, 0.f, 0.f};

    for (int g0i = 0; g0i < 4; ++g0i) {
        const int g0 = g0i * 64;

        // ---- A-bias chunk loaded DIRECTLY into the MFMA C-operand (accc);
        //      issued before the barriers so latency hides under K staging ----
        f32x4 accc[4];
#pragma unroll
        for (int ag = 0; ag < 4; ++ag) {
            const int gcol = g0 + 16*ag + c;
#pragma unroll
            for (int r = 0; r < 4; ++r) {
                const int hh = h0 + 16*wid + 4*quad + r;
                accc[ag][r] = wa0 * x2b[0*HW2 + hh*HW + gcol]
                            + wa1 * x2b[1*HW2 + hh*HW + gcol]
                            + wa2 * x2b[2*HW2 + hh*HW + gcol] + bav;
            }
        }

        __syncthreads();   // prev chunk's PV done reading sU(V^T) and sPc
        // ---- stage K rows g0..g0+63, full w=256 (row-major, w contiguous) ----
#pragma unroll
        for (int i = 0; i < 8; ++i) {
            const int s   = i*512 + tid;        // 0..4095
            const int row = s >> 6;
            const int c4  = (s & 63) * 4;
            const int g   = g0 + row;
            float4 u0 = *(const float4*)(x2b + 0*HW2 + g*HW + c4);
            float4 u1 = *(const float4*)(x2b + 1*HW2 + g*HW + c4);
            float4 u2 = *(const float4*)(x2b + 2*HW2 + g*HW + c4);
            bf16x4 kv;
            kv[0] = (__bf16)(wk0*u0.x + wk1*u1.x + wk2*u2.x + bkv);
            kv[1] = (__bf16)(wk0*u0.y + wk1*u1.y + wk2*u2.y + bkv);
            kv[2] = (__bf16)(wk0*u0.z + wk1*u1.z + wk2*u2.z + bkv);
            kv[3] = (__bf16)(wk0*u0.w + wk1*u1.w + wk2*u2.w + bkv);
            *(bf16x4*)(&sU[row*264 + c4]) = kv;
        }
        __syncthreads();

        // ---- S chunk = (Q/256)K^T + A ----
#pragma unroll
        for (int ag = 0; ag < 4; ++ag) {
            f32x4 a = accc[ag];
#pragma unroll
            for (int kt = 0; kt < 8; ++kt) {
                bf16x8 bf = *(const bf16x8*)(&sU[(16*ag + c)*264 + 32*kt + 8*quad]);
                a = __builtin_amdgcn_mfma_f32_16x16x32_bf16(qf[kt], bf, a, 0, 0, 0);
            }
            accc[ag] = a;
        }

        // ---- online softmax update (row = 4quad+r within wave) ----
        float fac[4];
#pragma unroll
        for (int r = 0; r < 4; ++r) {
            float mc = fmaxf(fmaxf(accc[0][r], accc[1][r]),
                             fmaxf(accc[2][r], accc[3][r]));
#pragma unroll
            for (int d = 8; d >= 1; d >>= 1) mc = fmaxf(mc, __shfl_xor(mc, d, 64));
            const float mn = fmaxf(m_run[r], mc);
            const float f  = __expf(m_run[r] - mn);   // 0 on first chunk
            m_run[r] = mn;
            fac[r] = f;
            float l = 0.0f;
#pragma unroll
            for (int ag = 0; ag < 4; ++ag) {
                float e = __expf(accc[ag][r] - mn);
                accc[ag][r] = e;
                l += e;
            }
#pragma unroll
            for (int d = 8; d >= 1; d >>= 1) l += __shfl_xor(l, d, 64);
            l_run[r] = l_run[r]*f + l;
        }
        if (c == 0) {
#pragma unroll
            for (int r = 0; r < 4; ++r) sFac[16*wid + 4*quad + r] = fac[r];
        }
        // write unnormalized P chunk (bf16), wave-private 16x64 tile
#pragma unroll
        for (int ag = 0; ag < 4; ++ag) {
#pragma unroll
            for (int r = 0; r < 4; ++r) {
                sPc[(16*wid + 4*quad + r)*72 + 16*ag + c] = (__bf16)accc[ag][r];
            }
        }
        __syncthreads();   // sPc/sFac ready; QK done reading sU(K)

        // ---- stage V^T (w-half): sU[w_local][gl], 128 rows x 64 g ----
        {
            const int wl = tid & 127;            // local w 0..127
            const int gb = (tid >> 7) * 16;      // 0,16,32,48
#pragma unroll
            for (int i = 0; i < 4; ++i) {
                const int gl = gb + i*4;
                const int g  = g0 + gl;
                bf16x4 pk;
#pragma unroll
                for (int j = 0; j < 4; ++j) {
                    float u0 = x2b[0*HW2 + (g+j)*HW + w0 + wl];
                    float u1 = x2b[1*HW2 + (g+j)*HW + w0 + wl];
                    float u2 = x2b[2*HW2 + (g+j)*HW + w0 + wl];
                    pk[j] = (__bf16)(wv0*u0 + wv1*u1 + wv2*u2 + bvv);
                }
                *(bf16x4*)(&sU[wl*72 + gl]) = pk;
            }
        }
        __syncthreads();

        // ---- PV: oacc = oacc*fac + V^T P^T (8 w-tiles) ----
        const float fc = sFac[16*wid + c];
        bf16x8 pf0 = *(const bf16x8*)(&sPc[(16*wid + c)*72 +  0 + 8*quad]);
        bf16x8 pf1 = *(const bf16x8*)(&sPc[(16*wid + c)*72 + 32 + 8*quad]);
#pragma unroll
        for (int wt = 0; wt < 8; ++wt) {
            f32x4 oa = oacc[wt];
            oa[0] *= fc; oa[1] *= fc; oa[2] *= fc; oa[3] *= fc;
            bf16x8 vf0 = *(const bf16x8*)(&sU[(16*wt + c)*72 +  0 + 8*quad]);
            oa = __builtin_amdgcn_mfma_f32_16x16x32_bf16(vf0, pf0, oa, 0, 0, 0);
            bf16x8 vf1 = *(const bf16x8*)(&sU[(16*wt + c)*72 + 32 + 8*quad]);
            oa = __builtin_amdgcn_mfma_f32_16x16x32_bf16(vf1, pf1, oa, 0, 0, 0);
            oacc[wt] = oa;
        }
    }

    // ---------- epilogue: normalize by row-sum, fp32 stores ----------
    if (c == 0) {
#pragma unroll
        for (int r = 0; r < 4; ++r) sRow[16*wid + 4*quad + r] = l_run[r];
    }
    __syncthreads();
    const float rinv = 1.0f / sRow[16*wid + c];
    float* outp = out + (size_t)pair * HW2 + (size_t)(h0 + 16*wid + c) * HW;
#pragma unroll
    for (int wt = 0; wt < 8; ++wt) {
#pragma unroll
        for (int r = 0; r < 4; ++r) {
            outp[w0 + 16*wt + 4*quad + r] = oacc[wt][r] * rinv;
        }
    }
}

extern "C" void kernel_launch(void* const* d_in, const int* in_sizes, int n_in,
                              void* d_out, int out_size, void* d_ws, size_t ws_size,
                              hipStream_t stream) {
    const float* x1 = (const float*)d_in[0];
    const float* x2 = (const float*)d_in[1];
    const float* Wq = (const float*)d_in[2];
    const float* bq = (const float*)d_in[3];
    const float* Wk = (const float*)d_in[4];
    const float* bk = (const float*)d_in[5];
    const float* Wv = (const float*)d_in[6];
    const float* bv = (const float*)d_in[7];
    const float* Wa = (const float*)d_in[8];
    const float* ba = (const float*)d_in[9];
    float* out = (float*)d_out;

    attn_kernel<<<dim3(4096), dim3(512), 0, stream>>>(
        x1, x2, Wq, bq, Wk, bk, Wv, bv, Wa, ba, out);
}

// Round 3
// 708.762 us; speedup vs baseline: 2.0009x; 2.0009x over previous
//
#include <hip/hip_runtime.h>

typedef __bf16 bf16x8 __attribute__((ext_vector_type(8)));
typedef __bf16 bf16x4 __attribute__((ext_vector_type(4)));
typedef float  f32x4  __attribute__((ext_vector_type(4)));

#define HW   256
#define HW2  65536

// 2048 blocks: (b,o) pair = blk>>1, h-tile = blk&1 (128 rows each).
// 512 threads = 8 waves; wave w owns h rows [h0+16w, h0+16w+16).
// Fused flash with double-buffered K and V^T in LDS, ONE barrier per chunk:
//   QK(i) [sK[p], ready] -> softmax -> sP/sFac (wave-local) ->
//   stage K(i+1),V(i+1) -> [p^1] + A(i+1)->accc -> PV(i) [sV[p]] -> barrier.
// LDS = 2x33.8K (K) + 2x36.9K (V^T) + 18.4K (P) + 1K = 157K -> 1 block/CU.
// launch_bounds(512,2): 256 regs/wave -> NO spills (r1/r2 lesson: 128-cap spills).
__global__ __launch_bounds__(512, 2) void attn_kernel(
    const float* __restrict__ x1, const float* __restrict__ x2,
    const float* __restrict__ Wq, const float* __restrict__ bq,
    const float* __restrict__ Wk, const float* __restrict__ bk,
    const float* __restrict__ Wv, const float* __restrict__ bv,
    const float* __restrict__ Wa, const float* __restrict__ ba,
    float* __restrict__ out)
{
    __shared__ __align__(16) __bf16 sK[2][64 * 264];   // 67584 B, K[g][w]
    __shared__ __align__(16) __bf16 sV[2][256 * 72];   // 73728 B, V^T[w][g]
    __shared__ __align__(16) __bf16 sP[128 * 72];      // 18432 B, P[h][g-chunk]
    __shared__ float sFac[128];                        // per-row rescale factor
    __shared__ float sRow[128];                        // final row sums

    const int tid  = threadIdx.x;
    const int wid  = tid >> 6;      // wave 0..7
    const int lane = tid & 63;
    const int quad = lane >> 4;     // 0..3
    const int c    = lane & 15;     // 0..15

    const int blk  = blockIdx.x;
    const int pair = blk >> 1;      // b*32 + o
    const int ht   = blk & 1;
    const int b    = pair >> 5;
    const int o    = pair & 31;
    const int h0   = ht * 128;

    const float wq0 = Wq[o*3+0], wq1 = Wq[o*3+1], wq2 = Wq[o*3+2], bqv = bq[o];
    const float wk0 = Wk[o*3+0], wk1 = Wk[o*3+1], wk2 = Wk[o*3+2], bkv = bk[o];
    const float wv0 = Wv[o*3+0], wv1 = Wv[o*3+1], wv2 = Wv[o*3+2], bvv = bv[o];
    const float wa0 = Wa[o*3+0], wa1 = Wa[o*3+1], wa2 = Wa[o*3+2], bav = ba[o];
    const float inv = 1.0f / 256.0f;

    const float* x1b = x1 + b * 3 * HW2;
    const float* x2b = x2 + b * 3 * HW2;

    // ---- staging / A-load helpers ----
#define STAGE_K(G0, DST)                                                      \
    {                                                                         \
        _Pragma("unroll")                                                     \
        for (int ii = 0; ii < 8; ++ii) {                                      \
            const int s_   = ii*512 + tid;                                    \
            const int row_ = s_ >> 6;                                         \
            const int c4_  = (s_ & 63) * 4;                                   \
            const int g_   = (G0) + row_;                                     \
            float4 u0 = *(const float4*)(x2b + 0*HW2 + g_*HW + c4_);          \
            float4 u1 = *(const float4*)(x2b + 1*HW2 + g_*HW + c4_);          \
            float4 u2 = *(const float4*)(x2b + 2*HW2 + g_*HW + c4_);          \
            bf16x4 kv;                                                        \
            kv[0] = (__bf16)(wk0*u0.x + wk1*u1.x + wk2*u2.x + bkv);           \
            kv[1] = (__bf16)(wk0*u0.y + wk1*u1.y + wk2*u2.y + bkv);           \
            kv[2] = (__bf16)(wk0*u0.z + wk1*u1.z + wk2*u2.z + bkv);           \
            kv[3] = (__bf16)(wk0*u0.w + wk1*u1.w + wk2*u2.w + bkv);           \
            *(bf16x4*)(&(DST)[row_*264 + c4_]) = kv;                          \
        }                                                                     \
    }

#define STAGE_V(G0, DST)                                                      \
    {                                                                         \
        const int w_  = tid & 255;                                            \
        const int gs_ = (tid >> 8) * 32;                                      \
        _Pragma("unroll")                                                     \
        for (int ii = 0; ii < 8; ++ii) {                                      \
            const int gl_ = gs_ + ii*4;                                       \
            const int g_  = (G0) + gl_;                                       \
            bf16x4 pk;                                                        \
            _Pragma("unroll")                                                 \
            for (int j = 0; j < 4; ++j) {                                     \
                float u0 = x2b[0*HW2 + (g_+j)*HW + w_];                       \
                float u1 = x2b[1*HW2 + (g_+j)*HW + w_];                       \
                float u2 = x2b[2*HW2 + (g_+j)*HW + w_];                       \
                pk[j] = (__bf16)(wv0*u0 + wv1*u1 + wv2*u2 + bvv);             \
            }                                                                 \
            *(bf16x4*)(&(DST)[w_*72 + gl_]) = pk;                             \
        }                                                                     \
    }

#define LOAD_A(G0, DST)                                                       \
    {                                                                         \
        _Pragma("unroll")                                                     \
        for (int ag = 0; ag < 4; ++ag) {                                      \
            const int gcol_ = (G0) + 16*ag + c;                               \
            _Pragma("unroll")                                                 \
            for (int r = 0; r < 4; ++r) {                                     \
                const int hh_ = h0 + 16*wid + 4*quad + r;                     \
                (DST)[ag][r] = wa0 * x2b[0*HW2 + hh_*HW + gcol_]              \
                             + wa1 * x2b[1*HW2 + hh_*HW + gcol_]              \
                             + wa2 * x2b[2*HW2 + hh_*HW + gcol_] + bav;       \
            }                                                                 \
        }                                                                     \
    }

    // ---------- Q fragments (A-operand), pre-scaled by inv_scale ----------
    bf16x8 qf[8];
    {
        const int hq = h0 + 16*wid + c;
        const float* r0 = x1b + 0*HW2 + hq*HW;
        const float* r1 = x1b + 1*HW2 + hq*HW;
        const float* r2 = x1b + 2*HW2 + hq*HW;
#pragma unroll
        for (int kt = 0; kt < 8; ++kt) {
            const int wc = 32*kt + 8*quad;
            float4 a0 = *(const float4*)(r0 + wc), a1 = *(const float4*)(r0 + wc + 4);
            float4 b0 = *(const float4*)(r1 + wc), b1 = *(const float4*)(r1 + wc + 4);
            float4 c0 = *(const float4*)(r2 + wc), c1 = *(const float4*)(r2 + wc + 4);
            bf16x8 q;
            q[0] = (__bf16)((wq0*a0.x + wq1*b0.x + wq2*c0.x + bqv) * inv);
            q[1] = (__bf16)((wq0*a0.y + wq1*b0.y + wq2*c0.y + bqv) * inv);
            q[2] = (__bf16)((wq0*a0.z + wq1*b0.z + wq2*c0.z + bqv) * inv);
            q[3] = (__bf16)((wq0*a0.w + wq1*b0.w + wq2*c0.w + bqv) * inv);
            q[4] = (__bf16)((wq0*a1.x + wq1*b1.x + wq2*c1.x + bqv) * inv);
            q[5] = (__bf16)((wq0*a1.y + wq1*b1.y + wq2*c1.y + bqv) * inv);
            q[6] = (__bf16)((wq0*a1.z + wq1*b1.z + wq2*c1.z + bqv) * inv);
            q[7] = (__bf16)((wq0*a1.w + wq1*b1.w + wq2*c1.w + bqv) * inv);
            qf[kt] = q;
        }
    }

    // O^T accumulator: oacc[wt] elem r = O^T[w=16wt+4quad+r][h=16wid+c]
    f32x4 oacc[16];
#pragma unroll
    for (int t = 0; t < 16; ++t) oacc[t] = (f32x4){0.f, 0.f, 0.f, 0.f};
    float m_run[4] = {-1e30f, -1e30f, -1e30f, -1e30f};
    float l_run[4] = {0.f, 0.f, 0.f, 0.f};

    // ---------- prologue: stage chunk 0, preload A(0) ----------
    f32x4 accc[4];
    STAGE_K(0, sK[0]);
    STAGE_V(0, sV[0]);
    LOAD_A(0, accc);
    __syncthreads();

    int p = 0;
#pragma unroll
    for (int i = 0; i < 4; ++i) {
        const int g0n = (i + 1) * 64;   // next chunk base

        // ---- QK(i): accc(=A chunk) += (Q/256)K^T — operands all ready ----
#pragma unroll
        for (int ag = 0; ag < 4; ++ag) {
            f32x4 a = accc[ag];
#pragma unroll
            for (int kt = 0; kt < 8; ++kt) {
                bf16x8 bf = *(const bf16x8*)(&sK[p][(16*ag + c)*264 + 32*kt + 8*quad]);
                a = __builtin_amdgcn_mfma_f32_16x16x32_bf16(qf[kt], bf, a, 0, 0, 0);
            }
            accc[ag] = a;
        }

        // ---- online softmax update (row = 4quad+r within wave) ----
        float fac[4];
#pragma unroll
        for (int r = 0; r < 4; ++r) {
            float mc = fmaxf(fmaxf(accc[0][r], accc[1][r]),
                             fmaxf(accc[2][r], accc[3][r]));
#pragma unroll
            for (int d = 8; d >= 1; d >>= 1) mc = fmaxf(mc, __shfl_xor(mc, d, 64));
            const float mn = fmaxf(m_run[r], mc);
            const float f  = __expf(m_run[r] - mn);   // 0 on first chunk
            m_run[r] = mn;
            fac[r] = f;
            float l = 0.0f;
#pragma unroll
            for (int ag = 0; ag < 4; ++ag) {
                float e = __expf(accc[ag][r] - mn);
                accc[ag][r] = e;
                l += e;
            }
#pragma unroll
            for (int d = 8; d >= 1; d >>= 1) l += __shfl_xor(l, d, 64);
            l_run[r] = l_run[r]*f + l;
        }
        if (c == 0) {
#pragma unroll
            for (int r = 0; r < 4; ++r) sFac[16*wid + 4*quad + r] = fac[r];
        }
        // write unnormalized P chunk (bf16) — wave-local rows, no barrier needed
#pragma unroll
        for (int ag = 0; ag < 4; ++ag) {
#pragma unroll
            for (int r = 0; r < 4; ++r) {
                sP[(16*wid + 4*quad + r)*72 + 16*ag + c] = (__bf16)accc[ag][r];
            }
        }

        // ---- stage next chunk into [p^1]; A(i+1) into freed accc ----
        // (independent of PV below — latency hides under PV MFMAs / wave drift)
        if (i < 3) {
            STAGE_K(g0n, sK[p^1]);
            STAGE_V(g0n, sV[p^1]);
            LOAD_A(g0n, accc);
        }

        // ---- PV(i): oacc = oacc*fac + V^T P^T  (reads sV[p], sP, sFac) ----
        {
            const float fc = sFac[16*wid + c];
            bf16x8 pf0 = *(const bf16x8*)(&sP[(16*wid + c)*72 +  0 + 8*quad]);
            bf16x8 pf1 = *(const bf16x8*)(&sP[(16*wid + c)*72 + 32 + 8*quad]);
#pragma unroll
            for (int wt = 0; wt < 16; ++wt) {
                f32x4 oa = oacc[wt];
                oa[0] *= fc; oa[1] *= fc; oa[2] *= fc; oa[3] *= fc;
                bf16x8 vf0 = *(const bf16x8*)(&sV[p][(16*wt + c)*72 +  0 + 8*quad]);
                oa = __builtin_amdgcn_mfma_f32_16x16x32_bf16(vf0, pf0, oa, 0, 0, 0);
                bf16x8 vf1 = *(const bf16x8*)(&sV[p][(16*wt + c)*72 + 32 + 8*quad]);
                oa = __builtin_amdgcn_mfma_f32_16x16x32_bf16(vf1, pf1, oa, 0, 0, 0);
                oacc[wt] = oa;
            }
        }

        __syncthreads();   // [p] fully consumed; [p^1] fully staged
        p ^= 1;
    }

    // ---------- epilogue: normalize by row-sum, fp32 stores ----------
    if (c == 0) {
#pragma unroll
        for (int r = 0; r < 4; ++r) sRow[16*wid + 4*quad + r] = l_run[r];
    }
    __syncthreads();
    const float rinv = 1.0f / sRow[16*wid + c];
    float* outp = out + (size_t)pair * HW2 + (size_t)(h0 + 16*wid + c) * HW;
#pragma unroll
    for (int wt = 0; wt < 16; ++wt) {
#pragma unroll
        for (int r = 0; r < 4; ++r) {
            outp[16*wt + 4*quad + r] = oacc[wt][r] * rinv;
        }
    }
#undef STAGE_K
#undef STAGE_V
#undef LOAD_A
}

extern "C" void kernel_launch(void* const* d_in, const int* in_sizes, int n_in,
                              void* d_out, int out_size, void* d_ws, size_t ws_size,
                              hipStream_t stream) {
    const float* x1 = (const float*)d_in[0];
    const float* x2 = (const float*)d_in[1];
    const float* Wq = (const float*)d_in[2];
    const float* bq = (const float*)d_in[3];
    const float* Wk = (const float*)d_in[4];
    const float* bk = (const float*)d_in[5];
    const float* Wv = (const float*)d_in[6];
    const float* bv = (const float*)d_in[7];
    const float* Wa = (const float*)d_in[8];
    const float* ba = (const float*)d_in[9];
    float* out = (float*)d_out;

    attn_kernel<<<dim3(2048), dim3(512), 0, stream>>>(
        x1, x2, Wq, bq, Wk, bk, Wv, bv, Wa, ba, out);
}